// Round 2
// baseline (103.570 us; speedup 1.0000x reference)
//
#include <hip/hip_runtime.h>
#include <math.h>

// Problem constants (DigitCapsules)
#define B_   64
#define IC   32
#define D_   288   // ICH*WID*HEI = 8*6*6
#define OC   10
#define OCH  16
#define J_   160   // OC*OCH
#define BJ   10240 // B_*J_

#define MAGIC 0x5CA1AB1E

// ws layout (floats):
//   US    [0,      327680) : [ic=32][b*160+j]
//   UDp   [327680, 332800) : [block=512][o=10] partial u_dot
//   nacc  [332800, 332803) : n accumulator per routing iteration
//   arr   [332804, 332807) : (int) per-iteration arrival counters
//   flags [332816, 333328) : (int[512]) per-block completion flags (MAGIC)
//
// SINGLE fused dispatch. Phase 1 (all 512 blocks = bt(16) x ic(32, minor ->
// XCD swizzle)): u_sum + u_dot partials, then release-publish a MAGIC flag.
// Poll-for-MAGIC needs NO initialized memory: ws is re-poisoned each launch
// (the 256 MiB fill visible in rocprof), and any poison != MAGIC works.
// Phase 2 (the 32 bt==0 blocks; 480 others exit -> no deadlock: spinners can
// never exhaust CU slots): wait for all 512 flags, acquire-fence (L2 inv ->
// US/UDp fresh cross-XCD), then ALL 3 routing iterations with s in registers;
// per-iteration grid sync is all-atomic (nacc add + ACQ_REL arrival counter),
// no fences in the loop. cs_q is recomputed bit-identically per block from
// the same UDp loads, so no cross-block css exchange exists.
__global__ __launch_bounds__(320) void k_all(const float* __restrict__ u,
                                             const float* __restrict__ Wt,
                                             float* __restrict__ US,
                                             float* __restrict__ UDp,
                                             float* __restrict__ nacc,
                                             int* __restrict__ arr,
                                             int* __restrict__ flags,
                                             float* __restrict__ out) {
    const int ic  = blockIdx.x & 31;
    const int bt  = blockIdx.x >> 5;    // 0..15
    const int tid = threadIdx.x;
    __shared__ float u_lds[4 * D_];     // [b_sub][d]
    __shared__ float part[640];         // dh=1 partials: [b_sub*40+j4] x float4
    __shared__ float ud_part[OC];
    __shared__ float cij[OC * IC];      // [o][i] (phase 2)
    __shared__ float wred[5];
    __shared__ float nsh;
    if (tid < OC) ud_part[tid] = 0.f;
    if (blockIdx.x == 0 && tid < 3) {   // zeroed BEFORE block 0's flag ->
        nacc[tid] = 0.f;                // visible to all routing blocks via
        arr[tid]  = 0;                  // the flag release/acquire protocol
    }
    // ---------------- phase 1: u_sum (identical math to k_usum) ----------
    for (int idx = tid; idx < 288; idx += 320) {
        int b_sub = idx / 72;
        int f4    = idx - b_sub * 72;
        int b     = bt * 4 + b_sub;
        ((float4*)u_lds)[idx] =
            ((const float4*)(u + (size_t)(b * IC + ic) * D_))[f4];
    }
    __syncthreads();
    {
        const int j4    = tid % 40;     // float4 index over j (lane-consecutive)
        const int b_sub = (tid / 40) & 3;
        const int dh    = tid / 160;    // d-half: 0 or 1
        const float4* wp = (const float4*)(Wt + (size_t)ic * D_ * J_)
                           + (size_t)dh * 144 * 40 + j4;
        const float*  ur = u_lds + b_sub * D_ + dh * 144;
        float ax = 0.f, ay = 0.f, az = 0.f, aw = 0.f;
        for (int d0 = 0; d0 < 144; d0 += 8) {
            float4 w0 = wp[(d0 + 0) * 40];
            float4 w1 = wp[(d0 + 1) * 40];
            float4 w2 = wp[(d0 + 2) * 40];
            float4 w3 = wp[(d0 + 3) * 40];
            float4 w4 = wp[(d0 + 4) * 40];
            float4 w5 = wp[(d0 + 5) * 40];
            float4 w6 = wp[(d0 + 6) * 40];
            float4 w7 = wp[(d0 + 7) * 40];
            float u0 = ur[d0 + 0], u1 = ur[d0 + 1], u2 = ur[d0 + 2], u3 = ur[d0 + 3];
            float u4 = ur[d0 + 4], u5 = ur[d0 + 5], u6 = ur[d0 + 6], u7 = ur[d0 + 7];
            ax += u0 * w0.x; ay += u0 * w0.y; az += u0 * w0.z; aw += u0 * w0.w;
            ax += u1 * w1.x; ay += u1 * w1.y; az += u1 * w1.z; aw += u1 * w1.w;
            ax += u2 * w2.x; ay += u2 * w2.y; az += u2 * w2.z; aw += u2 * w2.w;
            ax += u3 * w3.x; ay += u3 * w3.y; az += u3 * w3.z; aw += u3 * w3.w;
            ax += u4 * w4.x; ay += u4 * w4.y; az += u4 * w4.z; aw += u4 * w4.w;
            ax += u5 * w5.x; ay += u5 * w5.y; az += u5 * w5.z; aw += u5 * w5.w;
            ax += u6 * w6.x; ay += u6 * w6.y; az += u6 * w6.z; aw += u6 * w6.w;
            ax += u7 * w7.x; ay += u7 * w7.y; az += u7 * w7.z; aw += u7 * w7.w;
        }
        if (dh == 1) ((float4*)part)[tid - 160] = make_float4(ax, ay, az, aw);
        __syncthreads();
        if (dh == 0) {
            float4 p = ((float4*)part)[tid];
            ax += p.x; ay += p.y; az += p.z; aw += p.w;
            ((float4*)(US + (size_t)ic * BJ + (bt * 4 + b_sub) * J_))[j4] =
                make_float4(ax, ay, az, aw);
            float g = ax + ay + az + aw;
            g += __shfl_xor(g, 1);
            g += __shfl_xor(g, 2);
            if ((tid & 3) == 0) atomicAdd(&ud_part[j4 >> 2], g);
        }
    }
    __syncthreads();
    if (tid < OC) UDp[blockIdx.x * OC + tid] = ud_part[tid];
    __syncthreads();
    if (tid == 0) {
        __threadfence();   // agent release: write back US/UDp (+ block0's zeros)
        __hip_atomic_exchange(&flags[blockIdx.x], MAGIC,
                              __ATOMIC_RELEASE, __HIP_MEMORY_SCOPE_AGENT);
    }
    if (bt != 0) return;   // 480 blocks done

    // ---------------- phase 2: routing (blocks 0..31) --------------------
    if (tid < 256) {
        while (__hip_atomic_load(&flags[tid], __ATOMIC_RELAXED,
                                 __HIP_MEMORY_SCOPE_AGENT) != MAGIC ||
               __hip_atomic_load(&flags[tid + 256], __ATOMIC_RELAXED,
                                 __HIP_MEMORY_SCOPE_AGENT) != MAGIC)
            __builtin_amdgcn_s_sleep(2);
    }
    __syncthreads();
    __threadfence();       // acquire: invalidate L2 -> fresh US/UDp from L3

    const int i = tid & 31;            // in-capsule
    const int o = tid >> 5;            // 0..9
    float udv = 0.f;                   // same load order in every block ->
    #pragma unroll                     // bit-identical cs_q everywhere
    for (int b2 = 0; b2 < 16; ++b2) udv += UDp[(b2 * 32 + i) * OC + o];

    const int t  = blockIdx.x * 320 + tid;   // b*160 + o*16 + e
    const int ot = (t >> 4) % OC;
    const float* usp = US + t;

    float bij = 0.f;
    for (int q = 0; q < 3; ++q) {
        float s, cs;
        if (q == 0) {
            // b_ij = 0 -> c = 1/32 uniform; power-of-two scale is exact
            s = 0.f;
            #pragma unroll
            for (int ii = 0; ii < IC; ++ii) s += usp[(size_t)ii * BJ];
            s *= 0.03125f;
            cs = udv;
            cs += __shfl_xor(cs, 16, 32);
            cs += __shfl_xor(cs,  8, 32);
            cs += __shfl_xor(cs,  4, 32);
            cs += __shfl_xor(cs,  2, 32);
            cs += __shfl_xor(cs,  1, 32);
            cs *= 0.03125f;
        } else {
            // softmax over i (32 aligned lanes) for this o
            float m = bij;
            m = fmaxf(m, __shfl_xor(m, 16, 32));
            m = fmaxf(m, __shfl_xor(m,  8, 32));
            m = fmaxf(m, __shfl_xor(m,  4, 32));
            m = fmaxf(m, __shfl_xor(m,  2, 32));
            m = fmaxf(m, __shfl_xor(m,  1, 32));
            float e  = __expf(bij - m);
            float se = e;
            se += __shfl_xor(se, 16, 32);
            se += __shfl_xor(se,  8, 32);
            se += __shfl_xor(se,  4, 32);
            se += __shfl_xor(se,  2, 32);
            se += __shfl_xor(se,  1, 32);
            float c = e / se;
            cij[o * IC + i] = c;
            cs = c * udv;
            cs += __shfl_xor(cs, 16, 32);
            cs += __shfl_xor(cs,  8, 32);
            cs += __shfl_xor(cs,  4, 32);
            cs += __shfl_xor(cs,  2, 32);
            cs += __shfl_xor(cs,  1, 32);
            __syncthreads();           // cij visible
            s = 0.f;
            const float* cp = cij + ot * IC;
            #pragma unroll
            for (int ii = 0; ii < IC; ++ii) s += cp[ii] * usp[(size_t)ii * BJ];
        }
        // global n = sum |s| : block partial (fixed order) + 32 atomic adds
        float a = fabsf(s);
        #pragma unroll
        for (int off = 32; off; off >>= 1) a += __shfl_down(a, off);
        if ((tid & 63) == 0) wred[tid >> 6] = a;
        __syncthreads();
        if (tid == 0) {
            float blk = wred[0] + wred[1] + wred[2] + wred[3] + wred[4];
            atomicAdd(nacc + q, blk);
            __hip_atomic_fetch_add(&arr[q], 1, __ATOMIC_ACQ_REL,
                                   __HIP_MEMORY_SCOPE_AGENT);
            while (__hip_atomic_load(&arr[q], __ATOMIC_ACQUIRE,
                                     __HIP_MEMORY_SCOPE_AGENT) < 32)
                __builtin_amdgcn_s_sleep(1);
            nsh = __hip_atomic_load(nacc + q, __ATOMIC_RELAXED,
                                    __HIP_MEMORY_SCOPE_AGENT);
        }
        __syncthreads();
        const float n  = nsh;
        const float n2 = n * n;
        if (q < 2) {
            bij += udv * ((n2 / (1.f + n2)) * (cs / n));
        } else {
            out[t] = (n2 / (1.f + n2)) * (s / n);   // squash, s from registers
        }
    }
}

extern "C" void kernel_launch(void* const* d_in, const int* in_sizes, int n_in,
                              void* d_out, int out_size, void* d_ws, size_t ws_size,
                              hipStream_t stream) {
    (void)in_sizes; (void)n_in; (void)out_size; (void)ws_size;
    const float* u  = (const float*)d_in[0];
    const float* Wt = (const float*)d_in[1];
    float* ws    = (float*)d_ws;
    float* US    = ws;               // 327680 floats
    float* UDp   = ws + 327680;      // 5120 floats
    float* nacc  = ws + 332800;      // 3 floats
    int*   arr   = (int*)(ws + 332804);   // 3 ints
    int*   flags = (int*)(ws + 332816);   // 512 ints

    // ONE dispatch: grid barrier via MAGIC flags (no pre-init needed),
    // routing iterations via all-atomic arrival counters.
    k_all<<<dim3(512), dim3(320), 0, stream>>>(u, Wt, US, UDp, nacc, arr,
                                               flags, (float*)d_out);
}

// Round 3
// 98.946 us; speedup vs baseline: 1.0467x; 1.0467x over previous
//
#include <hip/hip_runtime.h>
#include <math.h>

// Problem constants (DigitCapsules)
#define B_   64
#define IC   32
#define D_   288   // ICH*WID*HEI = 8*6*6
#define OC   10
#define OCH  16
#define J_   160   // OC*OCH
#define BJ   10240 // B_*J_

#define MAGIC 0x5CA1AB1E

// ws layout (floats):
//   US    [0,      327680) : [ic=32][b*160+j]
//   UDp   [327680, 332800) : [block=512][o=10] partial u_dot
//   nacc  [332800, 332803) : n accumulator per routing iteration
//   arr   [332804, 332807) : (int) per-iteration arrival counters
//   flags [332816, 333328) : (int[512]) per-block completion flags (MAGIC)
//
// SINGLE fused dispatch.
// Phase 1 (512 blocks = bt(16) x ic(32, minor -> XCD swizzle)): u_sum with
// ZERO duplicated W traffic: thread = (dq in 8, j4 in 40), each thread owns
// ALL 4 b_sub (16 accumulators) over a disjoint 36-d slice, so each block
// issues exactly its 184 KB unique W slice (old layout issued 737 KB -> 4x
// L2 request/byte reduction; that duplication was the 30+ us stall at
// VALUBusy 3%). u staged TRANSPOSED in LDS (u_t[d][b_sub] float4) -> inner
// loop = 1 global float4 + 1 ds_read_b128 + 16 FMA. dq-partials reduced via
// LDS (ascending dq -> deterministic), then the old (j4,b_sub) US/u_dot/UDp
// epilogue unchanged.
// Phase 2 (32 bt==0 blocks; others exit): verbatim round-2 routing (passed),
// with longer poll sleeps so flag polling doesn't load the fabric while
// phase-1 stragglers finish.
__global__ __launch_bounds__(320) void k_all(const float* __restrict__ u,
                                             const float* __restrict__ Wt,
                                             float* __restrict__ US,
                                             float* __restrict__ UDp,
                                             float* __restrict__ nacc,
                                             int* __restrict__ arr,
                                             int* __restrict__ flags,
                                             float* __restrict__ out) {
    const int ic  = blockIdx.x & 31;
    const int bt  = blockIdx.x >> 5;    // 0..15
    const int tid = threadIdx.x;
    __shared__ float  u_t[D_ * 4];      // [d][b_sub] transposed, 4.6 KB
    __shared__ float4 part[8][4][40];   // [dq][b_sub][j4], 20 KB
    __shared__ float  ud_part[OC];
    __shared__ float  cij[OC * IC];     // [o][i] (phase 2)
    __shared__ float  wred[5];
    __shared__ float  nsh;
    if (tid < OC) ud_part[tid] = 0.f;
    if (blockIdx.x == 0 && tid < 3) {   // zeroed BEFORE block 0's flag ->
        nacc[tid] = 0.f;                // visible to routing blocks via the
        arr[tid]  = 0;                  // flag release/acquire protocol
    }
    // stage u transposed: 288 float4 coalesced loads, scatter to [d][b_sub]
    if (tid < 288) {
        const int b_sub = tid / 72;
        const int f4    = tid - b_sub * 72;
        const int b     = bt * 4 + b_sub;
        float4 v = ((const float4*)(u + (size_t)(b * IC + ic) * D_))[f4];
        u_t[(f4 * 4 + 0) * 4 + b_sub] = v.x;
        u_t[(f4 * 4 + 1) * 4 + b_sub] = v.y;
        u_t[(f4 * 4 + 2) * 4 + b_sub] = v.z;
        u_t[(f4 * 4 + 3) * 4 + b_sub] = v.w;
    }
    __syncthreads();
    // ---------------- phase 1 compute: no W duplication ------------------
    {
        const int j4 = tid % 40;
        const int dq = tid / 40;        // 0..7, disjoint 36-d slices
        const float4* wp = (const float4*)(Wt + (size_t)ic * D_ * J_)
                           + (size_t)(dq * 36) * 40 + j4;
        const float4* ut = ((const float4*)u_t) + dq * 36;
        float4 a0 = make_float4(0.f, 0.f, 0.f, 0.f);
        float4 a1 = a0, a2 = a0, a3 = a0;   // acc[b_sub], comps = j
#define ACC16(qv, wv)                                                        \
        a0.x += qv.x * wv.x; a0.y += qv.x * wv.y;                            \
        a0.z += qv.x * wv.z; a0.w += qv.x * wv.w;                            \
        a1.x += qv.y * wv.x; a1.y += qv.y * wv.y;                            \
        a1.z += qv.y * wv.z; a1.w += qv.y * wv.w;                            \
        a2.x += qv.z * wv.x; a2.y += qv.z * wv.y;                            \
        a2.z += qv.z * wv.z; a2.w += qv.z * wv.w;                            \
        a3.x += qv.w * wv.x; a3.y += qv.w * wv.y;                            \
        a3.z += qv.w * wv.z; a3.w += qv.w * wv.w;
        for (int k0 = 0; k0 < 36; k0 += 4) {
            float4 w0 = wp[(k0 + 0) * 40];
            float4 w1 = wp[(k0 + 1) * 40];
            float4 w2 = wp[(k0 + 2) * 40];
            float4 w3 = wp[(k0 + 3) * 40];
            float4 q0 = ut[k0 + 0];
            float4 q1 = ut[k0 + 1];
            float4 q2 = ut[k0 + 2];
            float4 q3 = ut[k0 + 3];
            ACC16(q0, w0)
            ACC16(q1, w1)
            ACC16(q2, w2)
            ACC16(q3, w3)
        }
#undef ACC16
        part[dq][0][j4] = a0;
        part[dq][1][j4] = a1;
        part[dq][2][j4] = a2;
        part[dq][3][j4] = a3;
    }
    __syncthreads();
    // reduce over dq (ascending -> deterministic), then old epilogue
    if (tid < 160) {
        const int jj = tid % 40;
        const int bs = tid / 40;
        float4 r = part[0][bs][jj];
        #pragma unroll
        for (int dq = 1; dq < 8; ++dq) {
            float4 p = part[dq][bs][jj];
            r.x += p.x; r.y += p.y; r.z += p.z; r.w += p.w;
        }
        ((float4*)(US + (size_t)ic * BJ + (bt * 4 + bs) * J_))[jj] = r;
        // u_dot partial: 4 consecutive lanes share o = jj>>2
        float g = r.x + r.y + r.z + r.w;
        g += __shfl_xor(g, 1);
        g += __shfl_xor(g, 2);
        if ((tid & 3) == 0) atomicAdd(&ud_part[jj >> 2], g);
    }
    __syncthreads();
    if (tid < OC) UDp[blockIdx.x * OC + tid] = ud_part[tid];
    __syncthreads();
    if (tid == 0) {
        __threadfence();   // agent release: write back US/UDp (+ block0 zeros)
        __hip_atomic_exchange(&flags[blockIdx.x], MAGIC,
                              __ATOMIC_RELEASE, __HIP_MEMORY_SCOPE_AGENT);
    }
    if (bt != 0) return;   // 480 blocks done

    // ---------------- phase 2: routing (blocks 0..31) --------------------
    if (tid < 256) {
        while (__hip_atomic_load(&flags[tid], __ATOMIC_RELAXED,
                                 __HIP_MEMORY_SCOPE_AGENT) != MAGIC ||
               __hip_atomic_load(&flags[tid + 256], __ATOMIC_RELAXED,
                                 __HIP_MEMORY_SCOPE_AGENT) != MAGIC)
            __builtin_amdgcn_s_sleep(16);
    }
    __syncthreads();
    __threadfence();       // acquire: fresh US/UDp cross-XCD

    const int i = tid & 31;            // in-capsule
    const int o = tid >> 5;            // 0..9
    float udv = 0.f;                   // same load order in every block ->
    #pragma unroll                     // bit-identical cs_q everywhere
    for (int b2 = 0; b2 < 16; ++b2) udv += UDp[(b2 * 32 + i) * OC + o];

    const int t  = blockIdx.x * 320 + tid;   // b*160 + o*16 + e
    const int ot = (t >> 4) % OC;
    const float* usp = US + t;

    float bij = 0.f;
    for (int q = 0; q < 3; ++q) {
        float s, cs;
        if (q == 0) {
            // b_ij = 0 -> c = 1/32 uniform; power-of-two scale is exact
            s = 0.f;
            #pragma unroll
            for (int ii = 0; ii < IC; ++ii) s += usp[(size_t)ii * BJ];
            s *= 0.03125f;
            cs = udv;
            cs += __shfl_xor(cs, 16, 32);
            cs += __shfl_xor(cs,  8, 32);
            cs += __shfl_xor(cs,  4, 32);
            cs += __shfl_xor(cs,  2, 32);
            cs += __shfl_xor(cs,  1, 32);
            cs *= 0.03125f;
        } else {
            // softmax over i (32 aligned lanes) for this o
            float m = bij;
            m = fmaxf(m, __shfl_xor(m, 16, 32));
            m = fmaxf(m, __shfl_xor(m,  8, 32));
            m = fmaxf(m, __shfl_xor(m,  4, 32));
            m = fmaxf(m, __shfl_xor(m,  2, 32));
            m = fmaxf(m, __shfl_xor(m,  1, 32));
            float e  = __expf(bij - m);
            float se = e;
            se += __shfl_xor(se, 16, 32);
            se += __shfl_xor(se,  8, 32);
            se += __shfl_xor(se,  4, 32);
            se += __shfl_xor(se,  2, 32);
            se += __shfl_xor(se,  1, 32);
            float c = e / se;
            cij[o * IC + i] = c;
            cs = c * udv;
            cs += __shfl_xor(cs, 16, 32);
            cs += __shfl_xor(cs,  8, 32);
            cs += __shfl_xor(cs,  4, 32);
            cs += __shfl_xor(cs,  2, 32);
            cs += __shfl_xor(cs,  1, 32);
            __syncthreads();           // cij visible
            s = 0.f;
            const float* cp = cij + ot * IC;
            #pragma unroll
            for (int ii = 0; ii < IC; ++ii) s += cp[ii] * usp[(size_t)ii * BJ];
        }
        // global n = sum |s| : block partial (fixed order) + 32 atomic adds
        float a = fabsf(s);
        #pragma unroll
        for (int off = 32; off; off >>= 1) a += __shfl_down(a, off);
        if ((tid & 63) == 0) wred[tid >> 6] = a;
        __syncthreads();
        if (tid == 0) {
            float blk = wred[0] + wred[1] + wred[2] + wred[3] + wred[4];
            atomicAdd(nacc + q, blk);
            __hip_atomic_fetch_add(&arr[q], 1, __ATOMIC_ACQ_REL,
                                   __HIP_MEMORY_SCOPE_AGENT);
            while (__hip_atomic_load(&arr[q], __ATOMIC_ACQUIRE,
                                     __HIP_MEMORY_SCOPE_AGENT) < 32)
                __builtin_amdgcn_s_sleep(4);
            nsh = __hip_atomic_load(nacc + q, __ATOMIC_RELAXED,
                                    __HIP_MEMORY_SCOPE_AGENT);
        }
        __syncthreads();
        const float n  = nsh;
        const float n2 = n * n;
        if (q < 2) {
            bij += udv * ((n2 / (1.f + n2)) * (cs / n));
        } else {
            out[t] = (n2 / (1.f + n2)) * (s / n);   // squash, s from registers
        }
    }
}

extern "C" void kernel_launch(void* const* d_in, const int* in_sizes, int n_in,
                              void* d_out, int out_size, void* d_ws, size_t ws_size,
                              hipStream_t stream) {
    (void)in_sizes; (void)n_in; (void)out_size; (void)ws_size;
    const float* u  = (const float*)d_in[0];
    const float* Wt = (const float*)d_in[1];
    float* ws    = (float*)d_ws;
    float* US    = ws;               // 327680 floats
    float* UDp   = ws + 327680;      // 5120 floats
    float* nacc  = ws + 332800;      // 3 floats
    int*   arr   = (int*)(ws + 332804);   // 3 ints
    int*   flags = (int*)(ws + 332816);   // 512 ints

    // ONE dispatch: grid barrier via MAGIC flags (no pre-init needed),
    // routing iterations via all-atomic arrival counters.
    k_all<<<dim3(512), dim3(320), 0, stream>>>(u, Wt, US, UDp, nacc, arr,
                                               flags, (float*)d_out);
}

// Round 4
// 74.284 us; speedup vs baseline: 1.3942x; 1.3320x over previous
//
#include <hip/hip_runtime.h>
#include <math.h>

// Problem constants (DigitCapsules)
#define B_   64
#define IC   32
#define D_   288   // ICH*WID*HEI = 8*6*6
#define OC   10
#define OCH  16
#define J_   160   // OC*OCH
#define BJ   10240 // B_*J_

// ws layout (floats):
//   US   [0,      327680) : [ic=32][b*160+j]
//   UDp  [327680, 332800) : [block=512][o=10] partial u_dot
//   nacc [332800, 332803) : n accumulator per routing iteration
//   bar  [332803]         : (int) arrival counter for k_route's barriers
//
// Structure: TWO dispatches (empirically: in-kernel agent-scope grid barriers
// cost ~10us each vs ~4-5us per kernel boundary; single-dispatch fusion lost).
//
// K1: u_sum with zero duplicated W traffic. thread = (dq in 8, j4 in 40);
// each thread owns ALL 4 b_sub (16 accumulators) over a disjoint 36-d slice,
// so each block issues exactly its 184 KB unique W slice. u staged TRANSPOSED
// in LDS (u_t[d][b_sub]); dq-partials reduced via LDS (ascending ->
// deterministic). grid 512 = bt(16) x ic(32, minor -> XCD = ic%8 so all 16
// blocks sharing an ic's W slice land on one XCD-L2). Also zero-inits
// nacc/bar for k_route (stream order).
__global__ __launch_bounds__(320) void k_usum(const float* __restrict__ u,
                                              const float* __restrict__ Wt,
                                              float* __restrict__ US,
                                              float* __restrict__ UDp,
                                              float* __restrict__ nacc,
                                              int* __restrict__ bar) {
    const int ic  = blockIdx.x & 31;
    const int bt  = blockIdx.x >> 5;    // 0..15
    const int tid = threadIdx.x;
    __shared__ float  u_t[D_ * 4];      // [d][b_sub] transposed
    __shared__ float4 part[8][4][40];   // [dq][b_sub][j4]
    __shared__ float  ud_part[OC];
    if (tid < OC) ud_part[tid] = 0.f;
    if (blockIdx.x == 0 && tid == 0) {
        nacc[0] = 0.f; nacc[1] = 0.f; nacc[2] = 0.f;
        *bar = 0;
    }
    // stage u transposed: 288 float4 coalesced loads, scatter to [d][b_sub]
    if (tid < 288) {
        const int b_sub = tid / 72;
        const int f4    = tid - b_sub * 72;
        const int b     = bt * 4 + b_sub;
        float4 v = ((const float4*)(u + (size_t)(b * IC + ic) * D_))[f4];
        u_t[(f4 * 4 + 0) * 4 + b_sub] = v.x;
        u_t[(f4 * 4 + 1) * 4 + b_sub] = v.y;
        u_t[(f4 * 4 + 2) * 4 + b_sub] = v.z;
        u_t[(f4 * 4 + 3) * 4 + b_sub] = v.w;
    }
    __syncthreads();
    {
        const int j4 = tid % 40;
        const int dq = tid / 40;        // 0..7, disjoint 36-d slices
        const float4* wp = (const float4*)(Wt + (size_t)ic * D_ * J_)
                           + (size_t)(dq * 36) * 40 + j4;
        const float4* ut = ((const float4*)u_t) + dq * 36;
        float4 a0 = make_float4(0.f, 0.f, 0.f, 0.f);
        float4 a1 = a0, a2 = a0, a3 = a0;   // acc[b_sub], comps = j
#define ACC16(qv, wv)                                                        \
        a0.x += qv.x * wv.x; a0.y += qv.x * wv.y;                            \
        a0.z += qv.x * wv.z; a0.w += qv.x * wv.w;                            \
        a1.x += qv.y * wv.x; a1.y += qv.y * wv.y;                            \
        a1.z += qv.y * wv.z; a1.w += qv.y * wv.w;                            \
        a2.x += qv.z * wv.x; a2.y += qv.z * wv.y;                            \
        a2.z += qv.z * wv.z; a2.w += qv.z * wv.w;                            \
        a3.x += qv.w * wv.x; a3.y += qv.w * wv.y;                            \
        a3.z += qv.w * wv.z; a3.w += qv.w * wv.w;
        for (int k0 = 0; k0 < 36; k0 += 4) {
            float4 w0 = wp[(k0 + 0) * 40];
            float4 w1 = wp[(k0 + 1) * 40];
            float4 w2 = wp[(k0 + 2) * 40];
            float4 w3 = wp[(k0 + 3) * 40];
            float4 q0 = ut[k0 + 0];
            float4 q1 = ut[k0 + 1];
            float4 q2 = ut[k0 + 2];
            float4 q3 = ut[k0 + 3];
            ACC16(q0, w0)
            ACC16(q1, w1)
            ACC16(q2, w2)
            ACC16(q3, w3)
        }
#undef ACC16
        part[dq][0][j4] = a0;
        part[dq][1][j4] = a1;
        part[dq][2][j4] = a2;
        part[dq][3][j4] = a3;
    }
    __syncthreads();
    // reduce over dq (ascending -> deterministic), then epilogue
    if (tid < 160) {
        const int jj = tid % 40;
        const int bs = tid / 40;
        float4 r = part[0][bs][jj];
        #pragma unroll
        for (int dq = 1; dq < 8; ++dq) {
            float4 p = part[dq][bs][jj];
            r.x += p.x; r.y += p.y; r.z += p.z; r.w += p.w;
        }
        ((float4*)(US + (size_t)ic * BJ + (bt * 4 + bs) * J_))[jj] = r;
        // u_dot partial: 4 consecutive lanes share o = jj>>2
        float g = r.x + r.y + r.z + r.w;
        g += __shfl_xor(g, 1);
        g += __shfl_xor(g, 2);
        if ((tid & 3) == 0) atomicAdd(&ud_part[jj >> 2], g);
    }
    __syncthreads();
    if (tid < OC) UDp[blockIdx.x * OC + tid] = ud_part[tid];
}

// K2: all 3 routing iterations + squash (round-0 proven kernel), with ONE
// change: the 32 US values each thread needs are iteration-invariant, so
// they're hoisted into registers (usv[32], fully unrolled -> static indexing,
// no scratch) before iteration 0. Per-iteration work is then pure
// register/LDS math + the 10-block barrier; no global re-reads exposed to
// the barrier's acquire-invalidations. grid 10 x 1024 = one t per thread.
__global__ __launch_bounds__(1024) void k_route(const float* __restrict__ US,
                                                const float* __restrict__ UDp,
                                                float* __restrict__ nacc,
                                                int* __restrict__ bar,
                                                float* __restrict__ out) {
    const int tid = threadIdx.x;
    const int i   = tid & 31;          // in-capsule (tid<320 path)
    const int o   = tid >> 5;          // 0..9     (tid<320 path)
    __shared__ float cij[OC * IC];     // [o][i]
    __shared__ float wred[16];
    __shared__ float nsh;
    float udv = 0.f;
    if (tid < 320) {                   // ud[i][o] = sum over 16 bt tiles
        #pragma unroll
        for (int bt = 0; bt < 16; ++bt) udv += UDp[(bt * 32 + i) * OC + o];
    }
    const int t  = blockIdx.x * 1024 + tid;   // b*160 + o*16 + e
    const int ot = (t >> 4) % OC;
    // hoist US column into registers: same values every iteration
    float usv[IC];
    {
        const float* usp = US + t;
        #pragma unroll
        for (int ii = 0; ii < IC; ++ii) usv[ii] = usp[(size_t)ii * BJ];
    }
    float bij = 0.f;
    for (int q = 0; q < 3; ++q) {
        float cs = 0.f;
        if (tid < 320) {
            // softmax over i (32 aligned lanes) for this o
            float m = bij;
            m = fmaxf(m, __shfl_xor(m, 16, 32));
            m = fmaxf(m, __shfl_xor(m,  8, 32));
            m = fmaxf(m, __shfl_xor(m,  4, 32));
            m = fmaxf(m, __shfl_xor(m,  2, 32));
            m = fmaxf(m, __shfl_xor(m,  1, 32));
            float e  = __expf(bij - m);
            float se = e;
            se += __shfl_xor(se, 16, 32);
            se += __shfl_xor(se,  8, 32);
            se += __shfl_xor(se,  4, 32);
            se += __shfl_xor(se,  2, 32);
            se += __shfl_xor(se,  1, 32);
            float c = e / se;
            cij[o * IC + i] = c;
            cs = c * udv;              // Σ_i c·ud for this o (butterfly)
            cs += __shfl_xor(cs, 16, 32);
            cs += __shfl_xor(cs,  8, 32);
            cs += __shfl_xor(cs,  4, 32);
            cs += __shfl_xor(cs,  2, 32);
            cs += __shfl_xor(cs,  1, 32);
        }
        __syncthreads();               // cij visible
        // s_t = Σ_i c[ot][i] * usv[i] — registers only
        float s = 0.f;
        {
            const float* cp = cij + ot * IC;
            #pragma unroll
            for (int ii = 0; ii < IC; ++ii) s += cp[ii] * usv[ii];
        }
        float a = fabsf(s);
        #pragma unroll
        for (int off = 32; off; off >>= 1) a += __shfl_down(a, off);
        if ((tid & 63) == 0) wred[tid >> 6] = a;
        __syncthreads();
        if (tid == 0) {
            float blk = 0.f;
            #pragma unroll
            for (int w = 0; w < 16; ++w) blk += wred[w];
            atomicAdd(nacc + q, blk);
            __threadfence();
            atomicAdd(bar, 1);
            while (__hip_atomic_load(bar, __ATOMIC_ACQUIRE,
                                     __HIP_MEMORY_SCOPE_AGENT) < 10 * (q + 1))
                __builtin_amdgcn_s_sleep(1);
            nsh = __hip_atomic_load(nacc + q, __ATOMIC_RELAXED,
                                    __HIP_MEMORY_SCOPE_AGENT);
        }
        __syncthreads();
        const float n  = nsh;
        const float n2 = n * n;
        if (q < 2) {
            if (tid < 320) bij += udv * ((n2 / (1.f + n2)) * (cs / n));
        } else {
            out[t] = (n2 / (1.f + n2)) * (s / n);
        }
    }
}

extern "C" void kernel_launch(void* const* d_in, const int* in_sizes, int n_in,
                              void* d_out, int out_size, void* d_ws, size_t ws_size,
                              hipStream_t stream) {
    (void)in_sizes; (void)n_in; (void)out_size; (void)ws_size;
    const float* u  = (const float*)d_in[0];
    const float* Wt = (const float*)d_in[1];
    float* ws   = (float*)d_ws;
    float* US   = ws;               // 327680 floats
    float* UDp  = ws + 327680;      // 5120 floats
    float* nacc = ws + 332800;      // 3 floats
    int*   bar  = (int*)(ws + 332803);

    // 2 dispatches. k_usum zero-inits nacc/bar (ws poisoned each launch);
    // stream order guarantees readiness + US/UDp visibility for k_route.
    k_usum <<<dim3(512), dim3(320),  0, stream>>>(u, Wt, US, UDp, nacc, bar);
    k_route<<<dim3(10),  dim3(1024), 0, stream>>>(US, UDp, nacc, bar, (float*)d_out);
}